// Round 10
// baseline (488.299 us; speedup 1.0000x reference)
//
#include <hip/hip_runtime.h>
#include <hip/hip_bf16.h>

#define NN 50000
#define NE 800000
#define EPSN 1e-12f

// Validated: f32 in/out; partitionable threefry dropout; exp w/o max-sub exact; bf16 FAILS;
// attn best = 12500 blk, 1 dst/wave, 4-edge unroll + analytic self-loop (R5/R7);
// gemm = 64-row tile, 4-row reg blocking, 16rgrp x 16cg (R9, validated); W in LDS (R8 global-W
// FAILED: latency-bound). R10: (a) gemm3 fused into attn2 epilogue (A2 store+load eliminated;
// RINV3 -> dead CURS buffer to avoid RINV race); (b) gemm1 split 391+391: hist hides under
// half A, scatter under half B; only scan chain exposed.

// ---- workspace layout (bytes, 16B aligned) ----
#define H_OFF    0ull          // f32 [50000][200] : H1 then H2
#define A_OFF    40000000ull   // f32 [50000][200] : A1
#define H3_OFF   80000000ull   // f32 [50000][2]
#define RINV_OFF 80400000ull   // f32 [50000]
#define OFFS_OFF 80600000ull   // int [50001]
#define DEG_OFF  80800016ull   // int [50000]
#define CURS_OFF 81000016ull   // int [50000] ; dead after scatter -> reused as f32 RINV3
#define ESRC_OFF 81200016ull   // int [800000]
#define CHNK_OFF 84600016ull   // int [64]

// ---------------- threefry2x32, 20 rounds ----------------
__host__ __device__ inline void tf20(unsigned k0, unsigned k1, unsigned& x0, unsigned& x1) {
  unsigned ks2 = k0 ^ k1 ^ 0x1BD11BDAu;
  x0 += k0; x1 += k1;
#define TFR(r) { x0 += x1; x1 = ((x1 << (r)) | (x1 >> (32 - (r)))) ^ x0; }
  TFR(13) TFR(15) TFR(26) TFR(6)
  x0 += k1;  x1 += ks2 + 1u;
  TFR(17) TFR(29) TFR(16) TFR(24)
  x0 += ks2; x1 += k0 + 2u;
  TFR(13) TFR(15) TFR(26) TFR(6)
  x0 += k0;  x1 += k1 + 3u;
  TFR(17) TFR(29) TFR(16) TFR(24)
  x0 += k1;  x1 += ks2 + 4u;
  TFR(13) TFR(15) TFR(26) TFR(6)
  x0 += ks2; x1 += k0 + 5u;
#undef TFR
}

__device__ __forceinline__ float dropf(float val, unsigned k0, unsigned k1, unsigned i) {
  unsigned x0 = 0u, x1 = i;
  tf20(k0, k1, x0, x1);
  unsigned bits = x0 ^ x1;
  float u = __uint_as_float((bits >> 9) | 0x3F800000u) - 1.0f;
  return (u < 0.9f) ? val * (1.0f / 0.9f) : 0.0f;
}

__device__ __forceinline__ float wave_sum(float x) {
  x += __shfl_xor(x, 32); x += __shfl_xor(x, 16); x += __shfl_xor(x, 8);
  x += __shfl_xor(x, 4);  x += __shfl_xor(x, 2);  x += __shfl_xor(x, 1);
  return x;
}

// ---------------- 4-row register-blocked tiled GEMM + fused row-norm (R9-validated) ---------
template<int K, int KT, int NLP, int N>
__device__ __forceinline__ void gemm_core4(float* __restrict__ As, float* __restrict__ Ws,
                                           const float* __restrict__ A,
                                           const float* __restrict__ W,
                                           float* __restrict__ H,
                                           float* __restrict__ RINV, int M, int row0) {
  static_assert(NLP % 64 == 0 && KT % 4 == 0, "layout");
  constexpr int KTP = KT + 1, NV = N / 4, NC = NLP / 64, PD4 = NLP / 4 - NV;
  const float4* A4 = (const float4*)A;
  const float4* W4 = (const float4*)W;
  const float4* Ws4 = (const float4*)Ws;

  int t = threadIdx.x, rgrp = t >> 4, cg = t & 15;
  float acc[4][NC * 4];
#pragma unroll
  for (int rr = 0; rr < 4; rr++)
#pragma unroll
    for (int j = 0; j < NC * 4; j++) acc[rr][j] = 0.f;

  for (int k0 = 0; k0 < K; k0 += KT) {
    __syncthreads();
    for (int idx = t; idx < 64 * (KT / 4); idx += 256) {
      int r = idx / (KT / 4), cq = idx - r * (KT / 4);
      int gr = row0 + r;
      float4 v = (gr < M) ? A4[(size_t)gr * (K / 4) + (k0 / 4) + cq]
                          : make_float4(0.f, 0.f, 0.f, 0.f);
      float* dst = &As[r * KTP + cq * 4];
      dst[0] = v.x; dst[1] = v.y; dst[2] = v.z; dst[3] = v.w;
    }
    for (int idx = t; idx < KT * NV; idx += 256) {
      int kk = idx / NV, cq = idx - kk * NV;
      *(float4*)&Ws[kk * NLP + cq * 4] = W4[(size_t)(k0 + kk) * NV + cq];
    }
    for (int idx = t; idx < KT * PD4; idx += 256) {
      int kk = idx / PD4, pq = idx - kk * PD4;
      *(float4*)&Ws[kk * NLP + N + pq * 4] = make_float4(0.f, 0.f, 0.f, 0.f);
    }
    __syncthreads();
#pragma unroll
    for (int kk = 0; kk < KT; kk++) {
      float a[4];
#pragma unroll
      for (int rr = 0; rr < 4; rr++) a[rr] = As[(rgrp * 4 + rr) * KTP + kk];
#pragma unroll
      for (int q = 0; q < NC; q++) {
        float4 wv = Ws4[kk * (NLP / 4) + cg + 16 * q];
#pragma unroll
        for (int rr = 0; rr < 4; rr++) {
          acc[rr][q * 4 + 0] = fmaf(a[rr], wv.x, acc[rr][q * 4 + 0]);
          acc[rr][q * 4 + 1] = fmaf(a[rr], wv.y, acc[rr][q * 4 + 1]);
          acc[rr][q * 4 + 2] = fmaf(a[rr], wv.z, acc[rr][q * 4 + 2]);
          acc[rr][q * 4 + 3] = fmaf(a[rr], wv.w, acc[rr][q * 4 + 3]);
        }
      }
    }
  }

  int r0 = row0 + rgrp * 4;
#pragma unroll
  for (int rr = 0; rr < 4; rr++) {
    int gr = r0 + rr;
    float ss = 0.f;
#pragma unroll
    for (int q = 0; q < NC; q++) {
#pragma unroll
      for (int j = 0; j < 4; j++) {
        float v = acc[rr][q * 4 + j];
        ss += v * v;                           // pad cols are exact 0
        int c = 4 * (cg + 16 * q) + j;
        if (gr < M && c < N) H[(size_t)gr * N + c] = v;
      }
    }
    ss += __shfl_xor(ss, 1); ss += __shfl_xor(ss, 2);
    ss += __shfl_xor(ss, 4); ss += __shfl_xor(ss, 8);
    if (cg == 0 && gr < M) RINV[gr] = 1.0f / fmaxf(sqrtf(ss), EPSN);
  }
}

// ---------------- front half A: gemm1 tiles 0..390 || edge histogram ----------------
__global__ __launch_bounds__(256, 4) void gemm1a_hist_kernel(
    const float* __restrict__ X, const float* __restrict__ W1,
    float* __restrict__ H, float* __restrict__ RINV,
    const int* __restrict__ EI, int* __restrict__ DEG) {
  __shared__ float As[64 * 17];
  __shared__ float Ws[16 * 256];
  int bid = blockIdx.x;
  if (bid < 391) {
    gemm_core4<128, 16, 256, 200>(As, Ws, X, W1, H, RINV, NN, bid * 64);
  } else {
    for (int e = (bid - 391) * 256 + threadIdx.x; e < NE; e += 242 * 256)
      atomicAdd(&DEG[EI[NE + e]], 1);
  }
}

// ---------------- front half B: gemm1 tiles 391..781 || edge scatter ----------------
__global__ __launch_bounds__(256, 4) void gemm1b_scat_kernel(
    const float* __restrict__ X, const float* __restrict__ W1,
    float* __restrict__ H, float* __restrict__ RINV,
    const int* __restrict__ EI, int* __restrict__ CURS,
    int* __restrict__ ESRC) {
  __shared__ float As[64 * 17];
  __shared__ float Ws[16 * 256];
  int bid = blockIdx.x;
  if (bid < 391) {
    gemm_core4<128, 16, 256, 200>(As, Ws, X, W1, H, RINV, NN, (bid + 391) * 64);
  } else {
    for (int e = (bid - 391) * 256 + threadIdx.x; e < NE; e += 242 * 256) {
      int s = EI[e], d = EI[NE + e];
      int pos = atomicAdd(&CURS[d], 1);
      ESRC[pos] = s;
    }
  }
}

__global__ __launch_bounds__(256, 4) void gemm2_kernel(const float* __restrict__ A,
                                                       const float* __restrict__ W,
                                                       float* __restrict__ H,
                                                       float* __restrict__ RINV, int M) {
  __shared__ float As[64 * 41];
  __shared__ float Ws[40 * 128];
  gemm_core4<200, 40, 128, 100>(As, Ws, A, W, H, RINV, M, blockIdx.x * 64);
}

// ---------------- CSR scan chain (hierarchical) ----------------
__global__ __launch_bounds__(256) void csr_scan1_kernel(const int* __restrict__ deg,
                                                        int* __restrict__ offs,
                                                        int* __restrict__ chunk) {
  __shared__ int lds[8];
  int t = threadIdx.x;
  int base = blockIdx.x * 1024 + t * 4;
  int d[4];
#pragma unroll
  for (int j = 0; j < 4; j++) d[j] = (base + j < NN) ? deg[base + j] : 0;
  int ts = d[0] + d[1] + d[2] + d[3];
  int lane = t & 63, wave = t >> 6;
  int inc = ts;
#pragma unroll
  for (int sh = 1; sh < 64; sh <<= 1) { int u = __shfl_up(inc, sh); if (lane >= sh) inc += u; }
  if (lane == 63) lds[wave] = inc;
  __syncthreads();
  if (t == 0) { int s = 0; for (int w = 0; w < 4; w++) { int x = lds[w]; lds[w] = s; s += x; } lds[4] = s; }
  __syncthreads();
  int p = lds[wave] + inc - ts;
#pragma unroll
  for (int j = 0; j < 4; j++) { if (base + j < NN) offs[base + j] = p; p += d[j]; }
  if (t == 255) chunk[blockIdx.x] = lds[4];
}

__global__ __launch_bounds__(64) void csr_scan2_kernel(int* __restrict__ chunk) {
  int t = threadIdx.x;
  int v = (t < 49) ? chunk[t] : 0;
  int inc = v;
#pragma unroll
  for (int sh = 1; sh < 64; sh <<= 1) { int u = __shfl_up(inc, sh); if (t >= sh) inc += u; }
  if (t < 49) chunk[t] = inc - v;
}

__global__ __launch_bounds__(256) void csr_scan3_kernel(int* __restrict__ offs,
                                                        const int* __restrict__ chunk,
                                                        int* __restrict__ curs) {
  int i = blockIdx.x * 256 + threadIdx.x;
  if (i < NN) {
    int val = offs[i] + chunk[i >> 10];
    offs[i] = val;
    curs[i] = val;
  }
  if (i == 0) offs[NN] = NE;
}

// ---------------- fused attention layer 1 (R7/R9-validated body) ----------------
template<int D, int VEC, bool DROP>
__device__ __forceinline__ void attn_body(const float* __restrict__ H,
                                          const float* __restrict__ RINV,
                                          const int* __restrict__ OFFS,
                                          const int* __restrict__ ESRC,
                                          const float* __restrict__ BETA,
                                          float* __restrict__ OUT,
                                          unsigned k0, unsigned k1) {
  constexpr int NL = D / VEC;
  int v = blockIdx.x * 4 + (threadIdx.x >> 6);
  int lane = threadIdx.x & 63;
  bool act = lane < NL;
  float beta = BETA[0];
  float bd = beta * RINV[v];
  int e0 = OFFS[v], e1 = OFFS[v + 1];

  float wself = __expf(beta);                  // analytic self-loop
  float s = wself;
  float hd[VEC], acc[VEC];
  if (act) {
    const float* hrow = H + (size_t)v * D + lane * VEC;
    if (VEC == 4) { float4 tv = *(const float4*)hrow; hd[0] = tv.x; hd[1] = tv.y; hd[2] = tv.z; hd[3] = tv.w; }
    else          { float2 tv = *(const float2*)hrow; hd[0] = tv.x; hd[1] = tv.y; }
#pragma unroll
    for (int j = 0; j < VEC; j++) acc[j] = wself * hd[j];
  }

  int idx = e0;
  for (; idx + 4 <= e1; idx += 4) {
    int   u[4];
    float r[4], dt[4], hs[4][VEC];
#pragma unroll
    for (int m = 0; m < 4; m++) u[m] = ESRC[idx + m];
#pragma unroll
    for (int m = 0; m < 4; m++) r[m] = RINV[u[m]];
    float dd[4] = {0.f, 0.f, 0.f, 0.f};
    if (act) {
#pragma unroll
      for (int m = 0; m < 4; m++) {
        const float* p = H + (size_t)u[m] * D + lane * VEC;
        if (VEC == 4) { float4 a = *(const float4*)p; hs[m][0] = a.x; hs[m][1] = a.y; hs[m][2] = a.z; hs[m][3] = a.w; }
        else          { float2 a = *(const float2*)p; hs[m][0] = a.x; hs[m][1] = a.y; }
      }
#pragma unroll
      for (int m = 0; m < 4; m++)
#pragma unroll
        for (int j = 0; j < VEC; j++) dd[m] = fmaf(hd[j], hs[m][j], dd[m]);
    }
#pragma unroll
    for (int m = 0; m < 4; m++) dt[m] = wave_sum(dd[m]);
    float w[4];
#pragma unroll
    for (int m = 0; m < 4; m++) { w[m] = __expf(bd * dt[m] * r[m]); s += w[m]; }
    if (act) {
#pragma unroll
      for (int m = 0; m < 4; m++)
#pragma unroll
        for (int j = 0; j < VEC; j++) acc[j] = fmaf(w[m], hs[m][j], acc[j]);
    }
  }
  for (; idx < e1; ++idx) {
    int u0 = ESRC[idx];
    float r0 = RINV[u0];
    float h0[VEC];
    float ddt = 0.f;
    if (act) {
      const float* p0 = H + (size_t)u0 * D + lane * VEC;
      if (VEC == 4) { float4 a = *(const float4*)p0; h0[0] = a.x; h0[1] = a.y; h0[2] = a.z; h0[3] = a.w; }
      else          { float2 a = *(const float2*)p0; h0[0] = a.x; h0[1] = a.y; }
#pragma unroll
      for (int j = 0; j < VEC; j++) ddt = fmaf(hd[j], h0[j], ddt);
    }
    ddt = wave_sum(ddt);
    float w0 = __expf(bd * ddt * r0);
    s += w0;
    if (act) {
#pragma unroll
      for (int j = 0; j < VEC; j++) acc[j] = fmaf(w0, h0[j], acc[j]);
    }
  }

  float rs = 1.0f / fmaxf(s, EPSN);
  if (act) {
    float o[VEC];
#pragma unroll
    for (int j = 0; j < VEC; j++) {
      float val = acc[j] * rs;
      val = (val <= 0.0f) ? 0.0f : val;
      if (DROP) val = dropf(val, k0, k1, (unsigned)(v * D + lane * VEC + j));
      o[j] = val;
    }
    float* orow = OUT + (size_t)v * D + lane * VEC;
    if (VEC == 4) *(float4*)orow = make_float4(o[0], o[1], o[2], o[3]);
    else          *(float2*)orow = make_float2(o[0], o[1]);
  }
}

__global__ __launch_bounds__(256) void attn1_kernel(const float* H, const float* RINV,
                                                    const int* OFFS, const int* ESRC,
                                                    const float* BETA, float* OUT,
                                                    unsigned k0, unsigned k1) {
  attn_body<200, 4, true>(H, RINV, OFFS, ESRC, BETA, OUT, k0, k1);
}

// ---------------- attn2 + fused layer-3 projection (gemm3 eliminated) ----------------
// Same D=100/VEC=2 body, but instead of storing A2, project the post-dropout row onto
// W3 (100x2): lane holds cols k=2*lane,2*lane+1 -> needs exactly float4 W3[4*lane].
// Two wave_sums produce H3[v][0..1]; RINV3 written to a SEPARATE buffer (dead CURS space)
// because other waves still read RINV[u] while this runs.
__global__ __launch_bounds__(256) void attn2_proj_kernel(
    const float* __restrict__ H, const float* __restrict__ RINV,
    const int* __restrict__ OFFS, const int* __restrict__ ESRC,
    const float* __restrict__ BETA, const float* __restrict__ W3,
    float* __restrict__ H3, float* __restrict__ RINV3,
    unsigned k0, unsigned k1) {
  constexpr int D = 100, VEC = 2, NL = 50;
  int v = blockIdx.x * 4 + (threadIdx.x >> 6);
  int lane = threadIdx.x & 63;
  bool act = lane < NL;
  float beta = BETA[0];
  float bd = beta * RINV[v];
  int e0 = OFFS[v], e1 = OFFS[v + 1];

  float4 w3v = make_float4(0.f, 0.f, 0.f, 0.f);
  if (act) w3v = *(const float4*)&W3[4 * lane];   // {w[k][0],w[k][1],w[k+1][0],w[k+1][1]}

  float wself = __expf(beta);
  float s = wself;
  float hd[VEC], acc[VEC];
  if (act) {
    const float* hrow = H + (size_t)v * D + lane * VEC;
    float2 tv = *(const float2*)hrow; hd[0] = tv.x; hd[1] = tv.y;
#pragma unroll
    for (int j = 0; j < VEC; j++) acc[j] = wself * hd[j];
  }

  int idx = e0;
  for (; idx + 4 <= e1; idx += 4) {
    int   u[4];
    float r[4], dt[4], hs[4][VEC];
#pragma unroll
    for (int m = 0; m < 4; m++) u[m] = ESRC[idx + m];
#pragma unroll
    for (int m = 0; m < 4; m++) r[m] = RINV[u[m]];
    float dd[4] = {0.f, 0.f, 0.f, 0.f};
    if (act) {
#pragma unroll
      for (int m = 0; m < 4; m++) {
        const float* p = H + (size_t)u[m] * D + lane * VEC;
        float2 a = *(const float2*)p; hs[m][0] = a.x; hs[m][1] = a.y;
      }
#pragma unroll
      for (int m = 0; m < 4; m++)
#pragma unroll
        for (int j = 0; j < VEC; j++) dd[m] = fmaf(hd[j], hs[m][j], dd[m]);
    }
#pragma unroll
    for (int m = 0; m < 4; m++) dt[m] = wave_sum(dd[m]);
    float w[4];
#pragma unroll
    for (int m = 0; m < 4; m++) { w[m] = __expf(bd * dt[m] * r[m]); s += w[m]; }
    if (act) {
#pragma unroll
      for (int m = 0; m < 4; m++)
#pragma unroll
        for (int j = 0; j < VEC; j++) acc[j] = fmaf(w[m], hs[m][j], acc[j]);
    }
  }
  for (; idx < e1; ++idx) {
    int u0 = ESRC[idx];
    float r0 = RINV[u0];
    float h0[VEC];
    float ddt = 0.f;
    if (act) {
      const float* p0 = H + (size_t)u0 * D + lane * VEC;
      float2 a = *(const float2*)p0; h0[0] = a.x; h0[1] = a.y;
#pragma unroll
      for (int j = 0; j < VEC; j++) ddt = fmaf(hd[j], h0[j], ddt);
    }
    ddt = wave_sum(ddt);
    float w0 = __expf(bd * ddt * r0);
    s += w0;
    if (act) {
#pragma unroll
      for (int j = 0; j < VEC; j++) acc[j] = fmaf(w0, h0[j], acc[j]);
    }
  }

  float rs = 1.0f / fmaxf(s, EPSN);
  float p0 = 0.f, p1 = 0.f;
  if (act) {
    float o[VEC];
#pragma unroll
    for (int j = 0; j < VEC; j++) {
      float val = acc[j] * rs;
      val = (val <= 0.0f) ? 0.0f : val;        // ReLU
      val = dropf(val, k0, k1, (unsigned)(v * D + lane * VEC + j));
      o[j] = val;
    }
    p0 = o[0] * w3v.x + o[1] * w3v.z;          // col 0 partial
    p1 = o[0] * w3v.y + o[1] * w3v.w;          // col 1 partial
  }
  p0 = wave_sum(p0);
  p1 = wave_sum(p1);
  if (lane == 0) {
    H3[2 * v] = p0; H3[2 * v + 1] = p1;
    RINV3[v] = 1.0f / fmaxf(sqrtf(p0 * p0 + p1 * p1), EPSN);
  }
}

// ---------------- layer-3 attention: lanes over edges + analytic self-loop ----------------
__global__ __launch_bounds__(256) void attn3_kernel(const float* __restrict__ H3,
                                                    const float* __restrict__ RINV3,
                                                    const int* __restrict__ OFFS,
                                                    const int* __restrict__ ESRC,
                                                    const float* __restrict__ BETA,
                                                    float* __restrict__ out) {
  int v = blockIdx.x * 4 + (threadIdx.x >> 6);
  int lane = threadIdx.x & 63;
  float beta = BETA[0];
  float bd = beta * RINV3[v];
  float h0 = H3[2 * v], h1 = H3[2 * v + 1];
  int e0 = OFFS[v], e1 = OFFS[v + 1];
  float s = 0.f, a0 = 0.f, a1 = 0.f;
  for (int idx = e0 + lane; idx < e1; idx += 64) {
    int u = ESRC[idx];
    float s0 = H3[2 * u], s1 = H3[2 * u + 1];
    float w = __expf(bd * (h0 * s0 + h1 * s1) * RINV3[u]);
    s += w; a0 = fmaf(w, s0, a0); a1 = fmaf(w, s1, a1);
  }
  s = wave_sum(s); a0 = wave_sum(a0); a1 = wave_sum(a1);
  if (lane == 0) {
    float wself = __expf(beta);
    s += wself; a0 = fmaf(wself, h0, a0); a1 = fmaf(wself, h1, a1);
    float rs = 1.0f / fmaxf(s, EPSN);
    float o0 = a0 * rs, o1 = a1 * rs;
    out[2 * v]     = (o0 <= 0.0f) ? 0.0f : o0;
    out[2 * v + 1] = (o1 <= 0.0f) ? 0.0f : o1;
  }
}

// ---------------- host ----------------
extern "C" void kernel_launch(void* const* d_in, const int* in_sizes, int n_in,
                              void* d_out, int out_size, void* d_ws, size_t ws_size,
                              hipStream_t stream) {
  const float* X  = (const float*)d_in[0];     // f32 [50000][128]
  const int*   EI = (const int*)d_in[1];
  const float* W1 = (const float*)d_in[2];
  const float* W2 = (const float*)d_in[3];
  const float* W3 = (const float*)d_in[4];
  const float* B1 = (const float*)d_in[5];
  const float* B2 = (const float*)d_in[6];
  const float* B3 = (const float*)d_in[7];

  char* ws = (char*)d_ws;
  float* H     = (float*)(ws + H_OFF);
  float* A     = (float*)(ws + A_OFF);
  float* H3    = (float*)(ws + H3_OFF);
  float* RINV  = (float*)(ws + RINV_OFF);
  int* OFFS    = (int*)(ws + OFFS_OFF);
  int* DEG     = (int*)(ws + DEG_OFF);
  int* CURS    = (int*)(ws + CURS_OFF);
  float* RINV3 = (float*)(ws + CURS_OFF);      // CURS dead after scatter; reuse as RINV3
  int* ESRC    = (int*)(ws + ESRC_OFF);
  int* CHNK    = (int*)(ws + CHNK_OFF);

  unsigned k1a = 0u, k1b = 0u; tf20(0u, 42u, k1a, k1b);
  unsigned k2a = 0u, k2b = 1u; tf20(0u, 42u, k2a, k2b);

  hipMemsetAsync(DEG, 0, NN * sizeof(int), stream);

  // front: gemm1 half A || hist -> scan chain -> gemm1 half B || scatter
  gemm1a_hist_kernel<<<633, 256, 0, stream>>>(X, W1, H, RINV, EI, DEG);
  csr_scan1_kernel<<<49, 256, 0, stream>>>(DEG, OFFS, CHNK);
  csr_scan2_kernel<<<1, 64, 0, stream>>>(CHNK);
  csr_scan3_kernel<<<196, 256, 0, stream>>>(OFFS, CHNK, CURS);
  gemm1b_scat_kernel<<<633, 256, 0, stream>>>(X, W1, H, RINV, EI, CURS, ESRC);

  const int gb = (NN + 63) / 64;     // 782
  const int ab = NN / 4;             // 12500

  // layer 1 attention
  attn1_kernel<<<ab, 256, 0, stream>>>(H, RINV, OFFS, ESRC, B1, A, k1a, k1b);
  // layer 2: 200 -> 100
  gemm2_kernel<<<gb, 256, 0, stream>>>(A, W2, H, RINV, NN);
  // layer 2 attention + fused layer-3 projection (A2/gemm3 eliminated)
  attn2_proj_kernel<<<ab, 256, 0, stream>>>(H, RINV, OFFS, ESRC, B2, W3, H3, RINV3, k2a, k2b);
  // layer 3 attention
  attn3_kernel<<<ab, 256, 0, stream>>>(H3, RINV3, OFFS, ESRC, B3, (float*)d_out);
}

// Round 11
// 464.718 us; speedup vs baseline: 1.0507x; 1.0507x over previous
//
#include <hip/hip_runtime.h>
#include <hip/hip_bf16.h>

#define NN 50000
#define NE 800000
#define EPSN 1e-12f

// Validated: f32 in/out; partitionable threefry dropout; exp w/o max-sub exact; bf16 FAILS;
// attn best = 12500 blk, 1 dst/wave, 4-edge unroll + analytic self-loop (R5/R7);
// gemm = 64-row tile, 4-row reg blocking (R9); gemm1||hist single 1024-blk launch (R9-best).
// R10 split-front FAILED (+16us: all blocks co-resident -> split = 2x tile-time serialized).
// R11 = R9 front (reverted) + gemm3-into-attn2 fusion kept (A2 store/load + launch removed;
// RINV3 in dead CURS buffer avoids RINV race).

// ---- workspace layout (bytes, 16B aligned) ----
#define H_OFF    0ull          // f32 [50000][200] : H1 then H2
#define A_OFF    40000000ull   // f32 [50000][200] : A1
#define H3_OFF   80000000ull   // f32 [50000][2]
#define RINV_OFF 80400000ull   // f32 [50000]
#define OFFS_OFF 80600000ull   // int [50001]
#define DEG_OFF  80800016ull   // int [50000]
#define CURS_OFF 81000016ull   // int [50000] ; dead after scatter -> reused as f32 RINV3
#define ESRC_OFF 81200016ull   // int [800000]
#define CHNK_OFF 84600016ull   // int [64]

// ---------------- threefry2x32, 20 rounds ----------------
__host__ __device__ inline void tf20(unsigned k0, unsigned k1, unsigned& x0, unsigned& x1) {
  unsigned ks2 = k0 ^ k1 ^ 0x1BD11BDAu;
  x0 += k0; x1 += k1;
#define TFR(r) { x0 += x1; x1 = ((x1 << (r)) | (x1 >> (32 - (r)))) ^ x0; }
  TFR(13) TFR(15) TFR(26) TFR(6)
  x0 += k1;  x1 += ks2 + 1u;
  TFR(17) TFR(29) TFR(16) TFR(24)
  x0 += ks2; x1 += k0 + 2u;
  TFR(13) TFR(15) TFR(26) TFR(6)
  x0 += k0;  x1 += k1 + 3u;
  TFR(17) TFR(29) TFR(16) TFR(24)
  x0 += k1;  x1 += ks2 + 4u;
  TFR(13) TFR(15) TFR(26) TFR(6)
  x0 += ks2; x1 += k0 + 5u;
#undef TFR
}

__device__ __forceinline__ float dropf(float val, unsigned k0, unsigned k1, unsigned i) {
  unsigned x0 = 0u, x1 = i;
  tf20(k0, k1, x0, x1);
  unsigned bits = x0 ^ x1;
  float u = __uint_as_float((bits >> 9) | 0x3F800000u) - 1.0f;
  return (u < 0.9f) ? val * (1.0f / 0.9f) : 0.0f;
}

__device__ __forceinline__ float wave_sum(float x) {
  x += __shfl_xor(x, 32); x += __shfl_xor(x, 16); x += __shfl_xor(x, 8);
  x += __shfl_xor(x, 4);  x += __shfl_xor(x, 2);  x += __shfl_xor(x, 1);
  return x;
}

// ---------------- 4-row register-blocked tiled GEMM + fused row-norm (R9-validated) ---------
template<int K, int KT, int NLP, int N>
__device__ __forceinline__ void gemm_core4(float* __restrict__ As, float* __restrict__ Ws,
                                           const float* __restrict__ A,
                                           const float* __restrict__ W,
                                           float* __restrict__ H,
                                           float* __restrict__ RINV, int M, int row0) {
  static_assert(NLP % 64 == 0 && KT % 4 == 0, "layout");
  constexpr int KTP = KT + 1, NV = N / 4, NC = NLP / 64, PD4 = NLP / 4 - NV;
  const float4* A4 = (const float4*)A;
  const float4* W4 = (const float4*)W;
  const float4* Ws4 = (const float4*)Ws;

  int t = threadIdx.x, rgrp = t >> 4, cg = t & 15;
  float acc[4][NC * 4];
#pragma unroll
  for (int rr = 0; rr < 4; rr++)
#pragma unroll
    for (int j = 0; j < NC * 4; j++) acc[rr][j] = 0.f;

  for (int k0 = 0; k0 < K; k0 += KT) {
    __syncthreads();
    for (int idx = t; idx < 64 * (KT / 4); idx += 256) {
      int r = idx / (KT / 4), cq = idx - r * (KT / 4);
      int gr = row0 + r;
      float4 v = (gr < M) ? A4[(size_t)gr * (K / 4) + (k0 / 4) + cq]
                          : make_float4(0.f, 0.f, 0.f, 0.f);
      float* dst = &As[r * KTP + cq * 4];
      dst[0] = v.x; dst[1] = v.y; dst[2] = v.z; dst[3] = v.w;
    }
    for (int idx = t; idx < KT * NV; idx += 256) {
      int kk = idx / NV, cq = idx - kk * NV;
      *(float4*)&Ws[kk * NLP + cq * 4] = W4[(size_t)(k0 + kk) * NV + cq];
    }
    for (int idx = t; idx < KT * PD4; idx += 256) {
      int kk = idx / PD4, pq = idx - kk * PD4;
      *(float4*)&Ws[kk * NLP + N + pq * 4] = make_float4(0.f, 0.f, 0.f, 0.f);
    }
    __syncthreads();
#pragma unroll
    for (int kk = 0; kk < KT; kk++) {
      float a[4];
#pragma unroll
      for (int rr = 0; rr < 4; rr++) a[rr] = As[(rgrp * 4 + rr) * KTP + kk];
#pragma unroll
      for (int q = 0; q < NC; q++) {
        float4 wv = Ws4[kk * (NLP / 4) + cg + 16 * q];
#pragma unroll
        for (int rr = 0; rr < 4; rr++) {
          acc[rr][q * 4 + 0] = fmaf(a[rr], wv.x, acc[rr][q * 4 + 0]);
          acc[rr][q * 4 + 1] = fmaf(a[rr], wv.y, acc[rr][q * 4 + 1]);
          acc[rr][q * 4 + 2] = fmaf(a[rr], wv.z, acc[rr][q * 4 + 2]);
          acc[rr][q * 4 + 3] = fmaf(a[rr], wv.w, acc[rr][q * 4 + 3]);
        }
      }
    }
  }

  int r0 = row0 + rgrp * 4;
#pragma unroll
  for (int rr = 0; rr < 4; rr++) {
    int gr = r0 + rr;
    float ss = 0.f;
#pragma unroll
    for (int q = 0; q < NC; q++) {
#pragma unroll
      for (int j = 0; j < 4; j++) {
        float v = acc[rr][q * 4 + j];
        ss += v * v;                           // pad cols are exact 0
        int c = 4 * (cg + 16 * q) + j;
        if (gr < M && c < N) H[(size_t)gr * N + c] = v;
      }
    }
    ss += __shfl_xor(ss, 1); ss += __shfl_xor(ss, 2);
    ss += __shfl_xor(ss, 4); ss += __shfl_xor(ss, 8);
    if (cg == 0 && gr < M) RINV[gr] = 1.0f / fmaxf(sqrtf(ss), EPSN);
  }
}

// ---------------- fused gemm1 || CSR-hist (R9-validated: single 1024-block launch) ----------
__global__ __launch_bounds__(256, 4) void gemm1_hist_kernel(
    const float* __restrict__ X, const float* __restrict__ W1,
    float* __restrict__ H, float* __restrict__ RINV,
    const int* __restrict__ EI, int* __restrict__ DEG) {
  __shared__ float As[64 * 17];
  __shared__ float Ws[16 * 256];
  int bid = blockIdx.x;
  if (bid < 782) {
    gemm_core4<128, 16, 256, 200>(As, Ws, X, W1, H, RINV, NN, bid * 64);
  } else {
    for (int e = (bid - 782) * 256 + threadIdx.x; e < NE; e += 242 * 256)
      atomicAdd(&DEG[EI[NE + e]], 1);
  }
}

__global__ __launch_bounds__(256, 4) void gemm2_kernel(const float* __restrict__ A,
                                                       const float* __restrict__ W,
                                                       float* __restrict__ H,
                                                       float* __restrict__ RINV, int M) {
  __shared__ float As[64 * 41];
  __shared__ float Ws[40 * 128];
  gemm_core4<200, 40, 128, 100>(As, Ws, A, W, H, RINV, M, blockIdx.x * 64);
}

// ---------------- CSR scan chain (hierarchical) ----------------
__global__ __launch_bounds__(256) void csr_scan1_kernel(const int* __restrict__ deg,
                                                        int* __restrict__ offs,
                                                        int* __restrict__ chunk) {
  __shared__ int lds[8];
  int t = threadIdx.x;
  int base = blockIdx.x * 1024 + t * 4;
  int d[4];
#pragma unroll
  for (int j = 0; j < 4; j++) d[j] = (base + j < NN) ? deg[base + j] : 0;
  int ts = d[0] + d[1] + d[2] + d[3];
  int lane = t & 63, wave = t >> 6;
  int inc = ts;
#pragma unroll
  for (int sh = 1; sh < 64; sh <<= 1) { int u = __shfl_up(inc, sh); if (lane >= sh) inc += u; }
  if (lane == 63) lds[wave] = inc;
  __syncthreads();
  if (t == 0) { int s = 0; for (int w = 0; w < 4; w++) { int x = lds[w]; lds[w] = s; s += x; } lds[4] = s; }
  __syncthreads();
  int p = lds[wave] + inc - ts;
#pragma unroll
  for (int j = 0; j < 4; j++) { if (base + j < NN) offs[base + j] = p; p += d[j]; }
  if (t == 255) chunk[blockIdx.x] = lds[4];
}

__global__ __launch_bounds__(64) void csr_scan2_kernel(int* __restrict__ chunk) {
  int t = threadIdx.x;
  int v = (t < 49) ? chunk[t] : 0;
  int inc = v;
#pragma unroll
  for (int sh = 1; sh < 64; sh <<= 1) { int u = __shfl_up(inc, sh); if (t >= sh) inc += u; }
  if (t < 49) chunk[t] = inc - v;
}

__global__ __launch_bounds__(256) void csr_scan3_kernel(int* __restrict__ offs,
                                                        const int* __restrict__ chunk,
                                                        int* __restrict__ curs) {
  int i = blockIdx.x * 256 + threadIdx.x;
  if (i < NN) {
    int val = offs[i] + chunk[i >> 10];
    offs[i] = val;
    curs[i] = val;
  }
  if (i == 0) offs[NN] = NE;
}

__global__ __launch_bounds__(256) void csr_scatter_kernel(const int* __restrict__ ei,
                                                          int* __restrict__ curs,
                                                          int* __restrict__ esrc) {
  int e = blockIdx.x * 256 + threadIdx.x;
  if (e >= NE) return;
  int s = ei[e], d = ei[NE + e];
  int pos = atomicAdd(&curs[d], 1);
  esrc[pos] = s;
}

// ---------------- fused attention layer 1 (R7/R9-validated body) ----------------
template<int D, int VEC, bool DROP>
__device__ __forceinline__ void attn_body(const float* __restrict__ H,
                                          const float* __restrict__ RINV,
                                          const int* __restrict__ OFFS,
                                          const int* __restrict__ ESRC,
                                          const float* __restrict__ BETA,
                                          float* __restrict__ OUT,
                                          unsigned k0, unsigned k1) {
  constexpr int NL = D / VEC;
  int v = blockIdx.x * 4 + (threadIdx.x >> 6);
  int lane = threadIdx.x & 63;
  bool act = lane < NL;
  float beta = BETA[0];
  float bd = beta * RINV[v];
  int e0 = OFFS[v], e1 = OFFS[v + 1];

  float wself = __expf(beta);                  // analytic self-loop
  float s = wself;
  float hd[VEC], acc[VEC];
  if (act) {
    const float* hrow = H + (size_t)v * D + lane * VEC;
    if (VEC == 4) { float4 tv = *(const float4*)hrow; hd[0] = tv.x; hd[1] = tv.y; hd[2] = tv.z; hd[3] = tv.w; }
    else          { float2 tv = *(const float2*)hrow; hd[0] = tv.x; hd[1] = tv.y; }
#pragma unroll
    for (int j = 0; j < VEC; j++) acc[j] = wself * hd[j];
  }

  int idx = e0;
  for (; idx + 4 <= e1; idx += 4) {
    int   u[4];
    float r[4], dt[4], hs[4][VEC];
#pragma unroll
    for (int m = 0; m < 4; m++) u[m] = ESRC[idx + m];
#pragma unroll
    for (int m = 0; m < 4; m++) r[m] = RINV[u[m]];
    float dd[4] = {0.f, 0.f, 0.f, 0.f};
    if (act) {
#pragma unroll
      for (int m = 0; m < 4; m++) {
        const float* p = H + (size_t)u[m] * D + lane * VEC;
        if (VEC == 4) { float4 a = *(const float4*)p; hs[m][0] = a.x; hs[m][1] = a.y; hs[m][2] = a.z; hs[m][3] = a.w; }
        else          { float2 a = *(const float2*)p; hs[m][0] = a.x; hs[m][1] = a.y; }
      }
#pragma unroll
      for (int m = 0; m < 4; m++)
#pragma unroll
        for (int j = 0; j < VEC; j++) dd[m] = fmaf(hd[j], hs[m][j], dd[m]);
    }
#pragma unroll
    for (int m = 0; m < 4; m++) dt[m] = wave_sum(dd[m]);
    float w[4];
#pragma unroll
    for (int m = 0; m < 4; m++) { w[m] = __expf(bd * dt[m] * r[m]); s += w[m]; }
    if (act) {
#pragma unroll
      for (int m = 0; m < 4; m++)
#pragma unroll
        for (int j = 0; j < VEC; j++) acc[j] = fmaf(w[m], hs[m][j], acc[j]);
    }
  }
  for (; idx < e1; ++idx) {
    int u0 = ESRC[idx];
    float r0 = RINV[u0];
    float h0[VEC];
    float ddt = 0.f;
    if (act) {
      const float* p0 = H + (size_t)u0 * D + lane * VEC;
      if (VEC == 4) { float4 a = *(const float4*)p0; h0[0] = a.x; h0[1] = a.y; h0[2] = a.z; h0[3] = a.w; }
      else          { float2 a = *(const float2*)p0; h0[0] = a.x; h0[1] = a.y; }
#pragma unroll
      for (int j = 0; j < VEC; j++) ddt = fmaf(hd[j], h0[j], ddt);
    }
    ddt = wave_sum(ddt);
    float w0 = __expf(bd * ddt * r0);
    s += w0;
    if (act) {
#pragma unroll
      for (int j = 0; j < VEC; j++) acc[j] = fmaf(w0, h0[j], acc[j]);
    }
  }

  float rs = 1.0f / fmaxf(s, EPSN);
  if (act) {
    float o[VEC];
#pragma unroll
    for (int j = 0; j < VEC; j++) {
      float val = acc[j] * rs;
      val = (val <= 0.0f) ? 0.0f : val;
      if (DROP) val = dropf(val, k0, k1, (unsigned)(v * D + lane * VEC + j));
      o[j] = val;
    }
    float* orow = OUT + (size_t)v * D + lane * VEC;
    if (VEC == 4) *(float4*)orow = make_float4(o[0], o[1], o[2], o[3]);
    else          *(float2*)orow = make_float2(o[0], o[1]);
  }
}

__global__ __launch_bounds__(256) void attn1_kernel(const float* H, const float* RINV,
                                                    const int* OFFS, const int* ESRC,
                                                    const float* BETA, float* OUT,
                                                    unsigned k0, unsigned k1) {
  attn_body<200, 4, true>(H, RINV, OFFS, ESRC, BETA, OUT, k0, k1);
}

// ---------------- attn2 + fused layer-3 projection (gemm3 eliminated; R10-validated) --------
__global__ __launch_bounds__(256) void attn2_proj_kernel(
    const float* __restrict__ H, const float* __restrict__ RINV,
    const int* __restrict__ OFFS, const int* __restrict__ ESRC,
    const float* __restrict__ BETA, const float* __restrict__ W3,
    float* __restrict__ H3, float* __restrict__ RINV3,
    unsigned k0, unsigned k1) {
  constexpr int D = 100, VEC = 2, NL = 50;
  int v = blockIdx.x * 4 + (threadIdx.x >> 6);
  int lane = threadIdx.x & 63;
  bool act = lane < NL;
  float beta = BETA[0];
  float bd = beta * RINV[v];
  int e0 = OFFS[v], e1 = OFFS[v + 1];

  float4 w3v = make_float4(0.f, 0.f, 0.f, 0.f);
  if (act) w3v = *(const float4*)&W3[4 * lane];   // {w[k][0],w[k][1],w[k+1][0],w[k+1][1]}

  float wself = __expf(beta);
  float s = wself;
  float hd[VEC], acc[VEC];
  if (act) {
    const float* hrow = H + (size_t)v * D + lane * VEC;
    float2 tv = *(const float2*)hrow; hd[0] = tv.x; hd[1] = tv.y;
#pragma unroll
    for (int j = 0; j < VEC; j++) acc[j] = wself * hd[j];
  }

  int idx = e0;
  for (; idx + 4 <= e1; idx += 4) {
    int   u[4];
    float r[4], dt[4], hs[4][VEC];
#pragma unroll
    for (int m = 0; m < 4; m++) u[m] = ESRC[idx + m];
#pragma unroll
    for (int m = 0; m < 4; m++) r[m] = RINV[u[m]];
    float dd[4] = {0.f, 0.f, 0.f, 0.f};
    if (act) {
#pragma unroll
      for (int m = 0; m < 4; m++) {
        const float* p = H + (size_t)u[m] * D + lane * VEC;
        float2 a = *(const float2*)p; hs[m][0] = a.x; hs[m][1] = a.y;
      }
#pragma unroll
      for (int m = 0; m < 4; m++)
#pragma unroll
        for (int j = 0; j < VEC; j++) dd[m] = fmaf(hd[j], hs[m][j], dd[m]);
    }
#pragma unroll
    for (int m = 0; m < 4; m++) dt[m] = wave_sum(dd[m]);
    float w[4];
#pragma unroll
    for (int m = 0; m < 4; m++) { w[m] = __expf(bd * dt[m] * r[m]); s += w[m]; }
    if (act) {
#pragma unroll
      for (int m = 0; m < 4; m++)
#pragma unroll
        for (int j = 0; j < VEC; j++) acc[j] = fmaf(w[m], hs[m][j], acc[j]);
    }
  }
  for (; idx < e1; ++idx) {
    int u0 = ESRC[idx];
    float r0 = RINV[u0];
    float h0[VEC];
    float ddt = 0.f;
    if (act) {
      const float* p0 = H + (size_t)u0 * D + lane * VEC;
      float2 a = *(const float2*)p0; h0[0] = a.x; h0[1] = a.y;
#pragma unroll
      for (int j = 0; j < VEC; j++) ddt = fmaf(hd[j], h0[j], ddt);
    }
    ddt = wave_sum(ddt);
    float w0 = __expf(bd * ddt * r0);
    s += w0;
    if (act) {
#pragma unroll
      for (int j = 0; j < VEC; j++) acc[j] = fmaf(w0, h0[j], acc[j]);
    }
  }

  float rs = 1.0f / fmaxf(s, EPSN);
  float p0 = 0.f, p1 = 0.f;
  if (act) {
    float o[VEC];
#pragma unroll
    for (int j = 0; j < VEC; j++) {
      float val = acc[j] * rs;
      val = (val <= 0.0f) ? 0.0f : val;        // ReLU
      val = dropf(val, k0, k1, (unsigned)(v * D + lane * VEC + j));
      o[j] = val;
    }
    p0 = o[0] * w3v.x + o[1] * w3v.z;          // col 0 partial
    p1 = o[0] * w3v.y + o[1] * w3v.w;          // col 1 partial
  }
  p0 = wave_sum(p0);
  p1 = wave_sum(p1);
  if (lane == 0) {
    H3[2 * v] = p0; H3[2 * v + 1] = p1;
    RINV3[v] = 1.0f / fmaxf(sqrtf(p0 * p0 + p1 * p1), EPSN);
  }
}

// ---------------- layer-3 attention: lanes over edges + analytic self-loop ----------------
__global__ __launch_bounds__(256) void attn3_kernel(const float* __restrict__ H3,
                                                    const float* __restrict__ RINV3,
                                                    const int* __restrict__ OFFS,
                                                    const int* __restrict__ ESRC,
                                                    const float* __restrict__ BETA,
                                                    float* __restrict__ out) {
  int v = blockIdx.x * 4 + (threadIdx.x >> 6);
  int lane = threadIdx.x & 63;
  float beta = BETA[0];
  float bd = beta * RINV3[v];
  float h0 = H3[2 * v], h1 = H3[2 * v + 1];
  int e0 = OFFS[v], e1 = OFFS[v + 1];
  float s = 0.f, a0 = 0.f, a1 = 0.f;
  for (int idx = e0 + lane; idx < e1; idx += 64) {
    int u = ESRC[idx];
    float s0 = H3[2 * u], s1 = H3[2 * u + 1];
    float w = __expf(bd * (h0 * s0 + h1 * s1) * RINV3[u]);
    s += w; a0 = fmaf(w, s0, a0); a1 = fmaf(w, s1, a1);
  }
  s = wave_sum(s); a0 = wave_sum(a0); a1 = wave_sum(a1);
  if (lane == 0) {
    float wself = __expf(beta);
    s += wself; a0 = fmaf(wself, h0, a0); a1 = fmaf(wself, h1, a1);
    float rs = 1.0f / fmaxf(s, EPSN);
    float o0 = a0 * rs, o1 = a1 * rs;
    out[2 * v]     = (o0 <= 0.0f) ? 0.0f : o0;
    out[2 * v + 1] = (o1 <= 0.0f) ? 0.0f : o1;
  }
}

// ---------------- host ----------------
extern "C" void kernel_launch(void* const* d_in, const int* in_sizes, int n_in,
                              void* d_out, int out_size, void* d_ws, size_t ws_size,
                              hipStream_t stream) {
  const float* X  = (const float*)d_in[0];     // f32 [50000][128]
  const int*   EI = (const int*)d_in[1];
  const float* W1 = (const float*)d_in[2];
  const float* W2 = (const float*)d_in[3];
  const float* W3 = (const float*)d_in[4];
  const float* B1 = (const float*)d_in[5];
  const float* B2 = (const float*)d_in[6];
  const float* B3 = (const float*)d_in[7];

  char* ws = (char*)d_ws;
  float* H     = (float*)(ws + H_OFF);
  float* A     = (float*)(ws + A_OFF);
  float* H3    = (float*)(ws + H3_OFF);
  float* RINV  = (float*)(ws + RINV_OFF);
  int* OFFS    = (int*)(ws + OFFS_OFF);
  int* DEG     = (int*)(ws + DEG_OFF);
  int* CURS    = (int*)(ws + CURS_OFF);
  float* RINV3 = (float*)(ws + CURS_OFF);      // CURS dead after scatter; reuse as RINV3
  int* ESRC    = (int*)(ws + ESRC_OFF);
  int* CHNK    = (int*)(ws + CHNK_OFF);

  unsigned k1a = 0u, k1b = 0u; tf20(0u, 42u, k1a, k1b);
  unsigned k2a = 0u, k2b = 1u; tf20(0u, 42u, k2a, k2b);

  hipMemsetAsync(DEG, 0, NN * sizeof(int), stream);

  // R9-validated front: fused gemm1 || hist, then scan chain, then scatter
  gemm1_hist_kernel<<<1024, 256, 0, stream>>>(X, W1, H, RINV, EI, DEG);
  csr_scan1_kernel<<<49, 256, 0, stream>>>(DEG, OFFS, CHNK);
  csr_scan2_kernel<<<1, 64, 0, stream>>>(CHNK);
  csr_scan3_kernel<<<196, 256, 0, stream>>>(OFFS, CHNK, CURS);
  csr_scatter_kernel<<<(NE + 255) / 256, 256, 0, stream>>>(EI, CURS, ESRC);

  const int gb = (NN + 63) / 64;     // 782
  const int ab = NN / 4;             // 12500

  // layer 1 attention
  attn1_kernel<<<ab, 256, 0, stream>>>(H, RINV, OFFS, ESRC, B1, A, k1a, k1b);
  // layer 2: 200 -> 100
  gemm2_kernel<<<gb, 256, 0, stream>>>(A, W2, H, RINV, NN);
  // layer 2 attention + fused layer-3 projection (A2/gemm3 eliminated)
  attn2_proj_kernel<<<ab, 256, 0, stream>>>(H, RINV, OFFS, ESRC, B2, W3, H3, RINV3, k2a, k2b);
  // layer 3 attention
  attn3_kernel<<<ab, 256, 0, stream>>>(H3, RINV3, OFFS, ESRC, B3, (float*)d_out);
}